// Round 12
// baseline (1172.953 us; speedup 1.0000x reference)
//
#include <hip/hip_runtime.h>

// Problem constants (from reference)
#define T_STEPS 100
#define BATCH   32
#define NIN     512
#define NN      2048
#define AREAS   2

// ALPHA = float(np.exp(-1e-3/1e-2)); cast to f32 at use-site.
#define ALPHA_D 0.9048374180359595

// ---------------------------------------------------------------------------
// k0: Poisson input spikes for ALL timesteps. f32 compare semantics.
__global__ __launch_bounds__(256)
void k0_xi(const float* __restrict__ rates, const float* __restrict__ noise,
           float* __restrict__ outXi, unsigned* __restrict__ xi_mask)
{
    int el = blockIdx.x * 256 + threadIdx.x;      // exact grid: 1,638,400
    float r = rates[el], nz = noise[el];
    float p = __fmul_rn(r, 0.001f);
    int spike = (nz < p) ? 1 : 0;
    outXi[el] = (float)spike;
    if (spike) {
        int t = el >> 14;
        int b = (el >> 9) & 31;
        int i = el & (NIN - 1);
        atomicOr(&xi_mask[(t * 32 + b) * 16 + (i >> 5)], 1u << (i & 31));
    }
}

// ---------------------------------------------------------------------------
// k_ff: feedforward currents Iff[t][b][a][n], one block per (tb, a).
__global__ __launch_bounds__(256)
void k_ff(const float* __restrict__ Win, const unsigned* __restrict__ xi_mask,
          float* __restrict__ Iff)
{
    const int tb  = blockIdx.x;      // t*32+b
    const int a   = blockIdx.y;
    const int tid = threadIdx.x;     // cols [8*tid, 8*tid+8)

    __shared__ unsigned mws[16];
    if (tid < 16) mws[tid] = xi_mask[tb * 16 + tid];
    __syncthreads();

    const float* Wa = Win + ((size_t)a << 20) + (tid << 3);
    float4 A0 = {0,0,0,0}, A1 = {0,0,0,0};
    for (int w = 0; w < 16; ++w) {
        unsigned mw = mws[w];
        int base_i = w << 5;
        while (mw) {
            int i = base_i + (__ffs(mw) - 1);
            mw &= mw - 1;
            const float* rp = Wa + ((size_t)i << 11);
            float4 w0 = ((const float4*)rp)[0];
            float4 w1 = ((const float4*)rp)[1];
            A0.x += w0.x; A0.y += w0.y; A0.z += w0.z; A0.w += w0.w;
            A1.x += w1.x; A1.y += w1.y; A1.z += w1.z; A1.w += w1.w;
        }
    }
    float* op = Iff + (((size_t)tb * 2 + a) << 11) + (tid << 3);
    ((float4*)op)[0] = A0;
    ((float4*)op)[1] = A1;
}

// ---------------------------------------------------------------------------
#define OFF_OF(rr) ((((rr) >> 11) << 23) + (((rr) & 2047) << 11))

// global -> LDS direct staging: one instruction stages 64 lanes x 16B = 1KB
// (this block's full 256-col slice of one Wrec row), vmcnt-counted, zero
// VGPRs held. Global src per-lane, LDS dst wave-uniform.
#define GLDS(src, dst) __builtin_amdgcn_global_load_lds(                      \
    (const __attribute__((address_space(1))) void*)(src),                     \
    (__attribute__((address_space(3))) void*)(dst), 16, 0, 0)

// ---------------------------------------------------------------------------
// k_steps v12: 512 blocks = 32 batches x 16 column-slices, 256 threads
// (1 dst col/thread). Post-mortem chain (us/step):
//   R0 14.5 | R2 33.7 | v3 16.7 | v4 12.1 | v5 10.6 | v6 9.6 | v7 10.7 |
//   v8 WRONG | v9 12.3 | v10 34.2 | v11 9.3 (best).
// v11's residual: (1) __syncthreads lowers with s_waitcnt vmcnt(0) -- each
// 64-row round fully drained before the next issued => gather still
// n_rounds x RT. (2) bx=b*16+s puts a CU's 2 blocks in the SAME batch:
// both stall on the same poll; CU idles every exchange RT.
// v12: (a) 8-phase-GEMM idiom for the gather -- 32-row rounds double-
// buffered across the two 32KB stage halves, raw s_barrier (no drain) +
// counted s_waitcnt vmcnt(8): issue r+1 (8 GLDS/wave), wait to 8
// outstanding (= round r landed; older accf/outS ops only make the wait
// conservative, vmcnt retires in order), barrier, consume r, barrier.
// RT hides under consume for all but first + partial-tail rounds.
// (b) remap s=(bx&7)|(((bx>>8)&1)<<3), b=(bx>>3)&31: keeps XCD<->column
// pinning EXACTLY (bx%8 = s&7 -> same FETCH dedup) while CU-paired blocks
// (bx,bx+8) become adjacent BATCHES -> desynchronized chains overlap
// poll-stall with gather. (c) poll sleep 4->1.
// Consume: strictly ascending rows, serial __fadd_rn per column --
// bit-exact (v6/v11's validated order). Sync = v5 data-is-the-barrier.
__global__ __launch_bounds__(256, 2)
void k_steps(const float* __restrict__ Wrec,
             unsigned long long* __restrict__ smask,  // [2][B][128] u64 tag|mask
             const float* __restrict__ Iff,           // [t][b][a][n]
             float* __restrict__ outS)                // out + T*B*NIN
{
    const int tid = threadIdx.x;               // 0..255
    const int bx  = blockIdx.x;
    const int s   = (bx & 7) | (((bx >> 8) & 1) << 3);   // slice 0..15
    const int b   = (bx >> 3) & 31;                      // batch
    const int a   = s >> 3;                    // dst area
    const int m0  = (s & 7) << 8;              // column-slice base
    const int c   = m0 + tid;                  // this thread's dst column
    const int wv  = tid >> 6;                  // wave 0..3
    const int lane = tid & 63;

    __shared__ __align__(16) float stage[64 * 256];            // 64 KB, 2 halves
    __shared__ unsigned mws[128];
    __shared__ __align__(16) unsigned short lrec[AREAS * NN];  // 8 KB
    __shared__ int base[128];
    __shared__ int cnt_rec;
    __shared__ unsigned nsp[8];

    // per-lane global src base: lane covers 16B (4 cols) of the block slice
    const float* __restrict__ Wb = Wrec + ((size_t)a << 22) + m0 + (lane << 2);
    const int rr_self = (a << 11) | c;
    const int wsel = rr_self >> 5;
    const int w0   = s << 3;                   // this block's 8 owned words

    float vst = 0.0f;

    for (int t = 0; t < T_STEPS; ++t) {
        unsigned long long* cur = smask + (size_t)(t & 1) * (BATCH * 128) + (b << 7);
        unsigned long long* nxt = smask + (size_t)((t + 1) & 1) * (BATCH * 128) + (b << 7);

        // ---- phase 1: data-spin -- each of 128 lanes polls its own
        //      tagged word (coalesced agent-scope loads)
        if (tid < 128) {
            unsigned long long v = __hip_atomic_load(&cur[tid], __ATOMIC_RELAXED,
                                                     __HIP_MEMORY_SCOPE_AGENT);
            while ((unsigned)(v >> 32) != (unsigned)t) {
                __builtin_amdgcn_s_sleep(1);
                v = __hip_atomic_load(&cur[tid], __ATOMIC_RELAXED,
                                      __HIP_MEMORY_SCOPE_AGENT);
            }
            mws[tid] = (unsigned)v;
        }
        if (tid < 8) nsp[tid] = 0u;
        float accf = Iff[((((size_t)t * BATCH + b) * 2 + a) << 11) + c];
        __syncthreads();

        // ---- phase 2: wave-0 prefix scan of mask popcounts
        if (tid < 64) {
            int c0 = __popc(mws[2 * tid]), c1 = __popc(mws[2 * tid + 1]);
            int cc = c0 + c1, incl = cc;
            #pragma unroll
            for (int d = 1; d < 64; d <<= 1) {
                int v = __shfl_up(incl, d, 64);
                if (tid >= d) incl += v;
            }
            base[2 * tid]     = incl - cc;
            base[2 * tid + 1] = incl - c1;
            if (tid == 63) cnt_rec = incl;
        }
        __syncthreads();

        // ---- phase 3: expand mask to ascending row list
        if (tid < 128) {
            unsigned w = mws[tid];
            if (w) {
                int off = base[tid];
                int bb = tid << 5;
                while (w) {
                    int p = __ffs(w) - 1;
                    lrec[off++] = (unsigned short)(bb + p);
                    w &= w - 1;
                }
            }
        }
        __syncthreads();

        const int nrec = cnt_rec;
        unsigned xd = (mws[wsel] >> (tid & 31)) & 1u;

        // ---- phase 4: pipelined burst-GLDS gather. Rounds of 32 rows x
        //      1KB double-buffered across stage halves; counted vmcnt(8)
        //      + raw s_barrier keep the next round in flight during
        //      consume. Ascending rows, serial __fadd_rn (bit-exact). ----
#define ISSUE_ROUND(r, h) do {                                                \
            const unsigned short* lp_ = &lrec[(r) << 5];                      \
            for (int k_ = wv; k_ < 32; k_ += 4)                               \
                GLDS(Wb + OFF_OF((int)lp_[k_]),                               \
                     &stage[((h) << 13) + (k_ << 8)]);                        \
        } while (0)

        float accr = 0.0f;
        const int nfull = nrec >> 5;
        const int rem   = nrec & 31;
        if (nfull > 0) {
            ISSUE_ROUND(0, 0);
            for (int r = 0; r < nfull; ++r) {
                const int h = r & 1;
                if (r + 1 < nfull) {
                    ISSUE_ROUND(r + 1, h ^ 1);
                    asm volatile("s_waitcnt vmcnt(8)" ::: "memory");
                } else {
                    asm volatile("s_waitcnt vmcnt(0)" ::: "memory");
                }
                __builtin_amdgcn_sched_barrier(0);     // rule #18 fence
                __builtin_amdgcn_s_barrier();          // round r visible
                const float* cb = &stage[h << 13];
                #pragma unroll 4
                for (int k = 0; k < 32; ++k)
                    accr = __fadd_rn(accr, cb[(k << 8) + tid]);
                __builtin_amdgcn_s_barrier();          // reads done pre-reuse
            }
        }
        if (rem) {
            const int h = nfull & 1;
            const unsigned short* lp = &lrec[nfull << 5];
            for (int k = wv; k < rem; k += 4)
                GLDS(Wb + OFF_OF((int)lp[k]), &stage[(h << 13) + (k << 8)]);
            asm volatile("s_waitcnt vmcnt(0)" ::: "memory");
            __builtin_amdgcn_sched_barrier(0);
            __builtin_amdgcn_s_barrier();
            const float* cb = &stage[h << 13];
            for (int k = 0; k < rem; ++k)
                accr = __fadd_rn(accr, cb[(k << 8) + tid]);
        }
#undef ISSUE_ROUND

        // ---- phase 5: LIF update, numpy f32 op-for-op ----
        float I  = __fadd_rn(accf, accr);
        float v  = __fmul_rn((float)ALPHA_D, vst);
        if (xd) v = 0.0f;
        float vn = __fadd_rn(v, I);
        vst = vn;
        int S = (vn >= 1.0f) ? 1 : 0;
        if (S) atomicOr(&nsp[tid >> 5], 1u << (tid & 31));
        __syncthreads();                       // nsp complete

        // ---- phase 6: publish tagged words FIRST, then outS store
        if (t < T_STEPS - 1 && tid < 8) {
            unsigned long long pv =
                ((unsigned long long)(unsigned)(t + 1) << 32) | nsp[tid];
            atomicExch(&nxt[w0 + tid], pv);    // RMW executes at CP (m20)
        }
        outS[(size_t)a * (T_STEPS * BATCH * NN)
             + (((size_t)t * BATCH + b) << 11) + c] = (float)S;
    }
}
#undef OFF_OF
#undef GLDS

// ---------------------------------------------------------------------------
extern "C" void kernel_launch(void* const* d_in, const int* in_sizes, int n_in,
                              void* d_out, int out_size, void* d_ws, size_t ws_size,
                              hipStream_t stream)
{
    const float* rates = (const float*)d_in[0];
    const float* noise = (const float*)d_in[1];
    const float* Win   = (const float*)d_in[2];
    const float* Wrec  = (const float*)d_in[3];
    float* out = (float*)d_out;

    // workspace layout (bytes):
    //   [0, 204800)           xi_mask uint32[T][B][16]
    //   [204800, 270336)      smask   u64[2][B][128]  (tag<<32 | mask)
    //   [270336, +52428800)   Iff     float[T][B][A][N]  (16B aligned)
    char* ws = (char*)d_ws;
    unsigned* xi_mask = (unsigned*)ws;
    unsigned long long* smask = (unsigned long long*)(ws + 204800);
    float* Iff = (float*)(ws + 270336);

    hipMemsetAsync(d_ws, 0, 270336, stream);   // zero xi_mask + smask

    k0_xi<<<6400, 256, 0, stream>>>(rates, noise, out, xi_mask);
    k_ff<<<dim3(3200, 2), 256, 0, stream>>>(Win, xi_mask, Iff);

    float* outS = out + (size_t)T_STEPS * BATCH * NIN;
    void* args[] = { (void*)&Wrec, (void*)&smask, (void*)&Iff, (void*)&outS };
    hipLaunchCooperativeKernel((const void*)k_steps, dim3(512), dim3(256),
                               args, 0, stream);
}